// Round 1
// baseline (523.962 us; speedup 1.0000x reference)
//
#include <hip/hip_runtime.h>
#include <hip/hip_bf16.h>
#include <stdint.h>

typedef short short8 __attribute__((ext_vector_type(8)));
typedef float f32x4 __attribute__((ext_vector_type(4)));
typedef unsigned short ushort_t;

static __device__ __forceinline__ unsigned short f2bf(float f) {
  union { float f; uint32_t u; } v; v.f = f;
  uint32_t u = v.u;
  return (unsigned short)((u + 0x7FFFu + ((u >> 16) & 1u)) >> 16);
}

static __device__ __forceinline__ float elu_f(float v) {
  return v > 0.0f ? v : expm1f(v);
}

// Pack W[K][Nc] (f32, row-major) into MFMA B-fragment order (bf16):
// dst[((nt*KT + kt)*64 + lane)*8 + i] = bf16(W[32*kt + 8*(lane>>4) + i][16*nt + (lane&15)])
__global__ void pack_kernel(const float* __restrict__ W, unsigned short* __restrict__ dst,
                            int KT, int Nc, int total) {
  int p = blockIdx.x * blockDim.x + threadIdx.x;
  if (p >= total) return;
  int i = p & 7;
  int l = (p >> 3) & 63;
  int rest = p >> 9;
  int kt = rest % KT;
  int nt = rest / KT;
  int krow = kt * 32 + (l >> 4) * 8 + i;
  int col = nt * 16 + (l & 15);
  dst[p] = f2bf(W[(size_t)krow * Nc + col]);
}

__global__ void count_kernel(const int* __restrict__ col_idx, int* __restrict__ cnt, int E) {
  int i = blockIdx.x * blockDim.x + threadIdx.x;
  if (i < E) atomicAdd(&cnt[col_idx[i]], 1);
}

#define LDA 264  // 256 + 8 pad (bf16 elems) -> row stride 528B, 16B aligned, banks spread

// 64 edges per block, 4 waves; wave w owns output cols [64w, 64w+64).
__global__ __launch_bounds__(256, 2) void edge_mlp_kernel(
    const float* __restrict__ x, const int* __restrict__ row_idx,
    const int* __restrict__ col_idx, const float* __restrict__ eattr,
    const float* __restrict__ b1a, const float* __restrict__ b1b,
    const unsigned short* __restrict__ w1aP, const unsigned short* __restrict__ w1bP,
    float* __restrict__ agg) {
  __shared__ unsigned short As[64 * LDA];
  __shared__ int rowi[64];
  __shared__ int dsti[64];
  const int t = threadIdx.x;
  const int e0 = blockIdx.x * 64;

  if (t < 64) {
    rowi[t] = row_idx[e0 + t];
    dsti[t] = col_idx[e0 + t];
  }
  __syncthreads();

  // stage A: [64 edges][256 feats] as bf16 (x[row] | edge_attr)
  for (int idx = t; idx < 64 * 64; idx += 256) {
    int e = idx >> 6, c4 = idx & 63;
    float4 v;
    if (c4 < 32)
      v = *(const float4*)(x + (size_t)rowi[e] * 128 + c4 * 4);
    else
      v = *(const float4*)(eattr + (size_t)(e0 + e) * 128 + (c4 - 32) * 4);
    ushort4 o;
    o.x = f2bf(v.x); o.y = f2bf(v.y); o.z = f2bf(v.z); o.w = f2bf(v.w);
    *(ushort4*)(&As[e * LDA + c4 * 4]) = o;
  }
  __syncthreads();

  const int w = t >> 6, l = t & 63;
  const int lr = l & 15, lk = l >> 4;

  f32x4 acc[4][4];
  const f32x4 zero4 = {0.f, 0.f, 0.f, 0.f};
#pragma unroll
  for (int mt = 0; mt < 4; ++mt)
#pragma unroll
    for (int nt = 0; nt < 4; ++nt) acc[mt][nt] = zero4;

  // GEMM1: [64,256] x W1a[256,256]
#pragma unroll
  for (int kt = 0; kt < 8; ++kt) {
    short8 a[4], b[4];
#pragma unroll
    for (int mt = 0; mt < 4; ++mt)
      a[mt] = *(const short8*)(&As[(mt * 16 + lr) * LDA + kt * 32 + lk * 8]);
#pragma unroll
    for (int nt = 0; nt < 4; ++nt) {
      int gn = w * 4 + nt;
      b[nt] = *(const short8*)(w1aP + ((size_t)(gn * 8 + kt) * 64 + l) * 8);
    }
#pragma unroll
    for (int mt = 0; mt < 4; ++mt)
#pragma unroll
      for (int nt = 0; nt < 4; ++nt)
        acc[mt][nt] = __builtin_amdgcn_mfma_f32_16x16x32_bf16(a[mt], b[nt], acc[mt][nt], 0, 0, 0);
  }
  __syncthreads();  // everyone done reading As

  // epilogue1: bias + ELU -> bf16, back into As (reused as H, stride LDA)
#pragma unroll
  for (int nt = 0; nt < 4; ++nt) {
    int col = w * 64 + nt * 16 + lr;
    float bias = b1a[col];
#pragma unroll
    for (int mt = 0; mt < 4; ++mt)
#pragma unroll
      for (int j = 0; j < 4; ++j) {
        float v = elu_f(acc[mt][nt][j] + bias);
        As[(mt * 16 + lk * 4 + j) * LDA + col] = f2bf(v);
      }
  }
  __syncthreads();

  // GEMM2: H[64,256] x W1b[256,256]
#pragma unroll
  for (int mt = 0; mt < 4; ++mt)
#pragma unroll
    for (int nt = 0; nt < 4; ++nt) acc[mt][nt] = zero4;
#pragma unroll
  for (int kt = 0; kt < 8; ++kt) {
    short8 a[4], b[4];
#pragma unroll
    for (int mt = 0; mt < 4; ++mt)
      a[mt] = *(const short8*)(&As[(mt * 16 + lr) * LDA + kt * 32 + lk * 8]);
#pragma unroll
    for (int nt = 0; nt < 4; ++nt) {
      int gn = w * 4 + nt;
      b[nt] = *(const short8*)(w1bP + ((size_t)(gn * 8 + kt) * 64 + l) * 8);
    }
#pragma unroll
    for (int mt = 0; mt < 4; ++mt)
#pragma unroll
      for (int nt = 0; nt < 4; ++nt)
        acc[mt][nt] = __builtin_amdgcn_mfma_f32_16x16x32_bf16(a[mt], b[nt], acc[mt][nt], 0, 0, 0);
  }

  // epilogue2: bias + scatter atomic-add into agg[dst]
#pragma unroll
  for (int nt = 0; nt < 4; ++nt) {
    int col = w * 64 + nt * 16 + lr;
    float bias = b1b[col];
#pragma unroll
    for (int mt = 0; mt < 4; ++mt)
#pragma unroll
      for (int j = 0; j < 4; ++j) {
        int row = mt * 16 + lk * 4 + j;
        int d = dsti[row];
        atomicAdd(&agg[(size_t)d * 256 + col], acc[mt][nt][j] + bias);
      }
  }
}

#define LDN 392  // 384 + 8 pad

// 64 nodes per block, 4 waves. GEMM1: K=384 -> 256 (ELU), GEMM2: K=256 -> 128.
__global__ __launch_bounds__(256, 2) void node_mlp_kernel(
    const float* __restrict__ x, const float* __restrict__ agg, const int* __restrict__ cnt,
    const float* __restrict__ b2a, const float* __restrict__ b2b,
    const unsigned short* __restrict__ w2aP, const unsigned short* __restrict__ w2bP,
    float* __restrict__ out, int N) {
  __shared__ unsigned short As[64 * LDN];
  const int t = threadIdx.x;
  const int n0 = blockIdx.x * 64;

  // stage A: [64 nodes][384] = bf16( x[n] | agg[n]/max(cnt,1) )
  for (int idx = t; idx < 64 * 96; idx += 256) {
    int nn = idx / 96;
    int c4 = idx - nn * 96;
    int node = n0 + nn;
    float4 v = {0.f, 0.f, 0.f, 0.f};
    if (node < N) {
      if (c4 < 32) {
        v = *(const float4*)(x + (size_t)node * 128 + c4 * 4);
      } else {
        float inv = 1.0f / fmaxf((float)cnt[node], 1.0f);
        float4 s = *(const float4*)(agg + (size_t)node * 256 + (c4 - 32) * 4);
        v.x = s.x * inv; v.y = s.y * inv; v.z = s.z * inv; v.w = s.w * inv;
      }
    }
    ushort4 o;
    o.x = f2bf(v.x); o.y = f2bf(v.y); o.z = f2bf(v.z); o.w = f2bf(v.w);
    *(ushort4*)(&As[nn * LDN + c4 * 4]) = o;
  }
  __syncthreads();

  const int w = t >> 6, l = t & 63;
  const int lr = l & 15, lk = l >> 4;
  const f32x4 zero4 = {0.f, 0.f, 0.f, 0.f};

  f32x4 acc[4][4];
#pragma unroll
  for (int mt = 0; mt < 4; ++mt)
#pragma unroll
    for (int nt = 0; nt < 4; ++nt) acc[mt][nt] = zero4;

  // GEMM1: [64,384] x W2a[384,256]
#pragma unroll
  for (int kt = 0; kt < 12; ++kt) {
    short8 a[4], b[4];
#pragma unroll
    for (int mt = 0; mt < 4; ++mt)
      a[mt] = *(const short8*)(&As[(mt * 16 + lr) * LDN + kt * 32 + lk * 8]);
#pragma unroll
    for (int nt = 0; nt < 4; ++nt) {
      int gn = w * 4 + nt;
      b[nt] = *(const short8*)(w2aP + ((size_t)(gn * 12 + kt) * 64 + l) * 8);
    }
#pragma unroll
    for (int mt = 0; mt < 4; ++mt)
#pragma unroll
      for (int nt = 0; nt < 4; ++nt)
        acc[mt][nt] = __builtin_amdgcn_mfma_f32_16x16x32_bf16(a[mt], b[nt], acc[mt][nt], 0, 0, 0);
  }
  __syncthreads();  // done reading As

  // epilogue1: bias + ELU -> H (reuse As, stride 264)
#pragma unroll
  for (int nt = 0; nt < 4; ++nt) {
    int col = w * 64 + nt * 16 + lr;
    float bias = b2a[col];
#pragma unroll
    for (int mt = 0; mt < 4; ++mt)
#pragma unroll
      for (int j = 0; j < 4; ++j) {
        float v = elu_f(acc[mt][nt][j] + bias);
        As[(mt * 16 + lk * 4 + j) * 264 + col] = f2bf(v);
      }
  }
  __syncthreads();

  // GEMM2: H[64,256] x W2b[256,128]; wave w owns cols [32w, 32w+32)
  f32x4 acc2[4][2];
#pragma unroll
  for (int mt = 0; mt < 4; ++mt)
#pragma unroll
    for (int nt = 0; nt < 2; ++nt) acc2[mt][nt] = zero4;
#pragma unroll
  for (int kt = 0; kt < 8; ++kt) {
    short8 a[4], b[2];
#pragma unroll
    for (int mt = 0; mt < 4; ++mt)
      a[mt] = *(const short8*)(&As[(mt * 16 + lr) * 264 + kt * 32 + lk * 8]);
#pragma unroll
    for (int nt = 0; nt < 2; ++nt) {
      int gn = w * 2 + nt;
      b[nt] = *(const short8*)(w2bP + ((size_t)(gn * 8 + kt) * 64 + l) * 8);
    }
#pragma unroll
    for (int mt = 0; mt < 4; ++mt)
#pragma unroll
      for (int nt = 0; nt < 2; ++nt)
        acc2[mt][nt] = __builtin_amdgcn_mfma_f32_16x16x32_bf16(a[mt], b[nt], acc2[mt][nt], 0, 0, 0);
  }

  // epilogue2: bias + store
#pragma unroll
  for (int nt = 0; nt < 2; ++nt) {
    int col = w * 32 + nt * 16 + lr;
    float bias = b2b[col];
#pragma unroll
    for (int mt = 0; mt < 4; ++mt)
#pragma unroll
      for (int j = 0; j < 4; ++j) {
        int node = n0 + mt * 16 + lk * 4 + j;
        if (node < N) out[(size_t)node * 128 + col] = acc2[mt][nt][j] + bias;
      }
  }
}

extern "C" void kernel_launch(void* const* d_in, const int* in_sizes, int n_in,
                              void* d_out, int out_size, void* d_ws, size_t ws_size,
                              hipStream_t stream) {
  const float* x = (const float*)d_in[0];
  const int* ei = (const int*)d_in[1];
  const float* eattr = (const float*)d_in[2];
  // d_in[3] = u, d_in[4] = batch : unused by the reference
  const float* W1a = (const float*)d_in[5];
  const float* b1a = (const float*)d_in[6];
  const float* W1b = (const float*)d_in[7];
  const float* b1b = (const float*)d_in[8];
  const float* W2a = (const float*)d_in[9];
  const float* b2a = (const float*)d_in[10];
  const float* W2b = (const float*)d_in[11];
  const float* b2b = (const float*)d_in[12];

  const int N = in_sizes[0] / 128;   // 25000
  const int E = in_sizes[2] / 128;   // 400000

  char* ws = (char*)d_ws;
  float* agg = (float*)ws;                                   // N*256 f32
  int* cnt = (int*)(ws + (size_t)N * 256 * 4);               // N int
  size_t off = (size_t)N * 256 * 4 + (size_t)N * 4;
  off = (off + 255) & ~(size_t)255;
  unsigned short* w1aP = (unsigned short*)(ws + off); off += 256 * 256 * 2;
  unsigned short* w1bP = (unsigned short*)(ws + off); off += 256 * 256 * 2;
  unsigned short* w2aP = (unsigned short*)(ws + off); off += 384 * 256 * 2;
  unsigned short* w2bP = (unsigned short*)(ws + off); off += 256 * 128 * 2;

  // zero agg sums + counts (accumulated via atomics each launch)
  hipMemsetAsync(ws, 0, (size_t)N * 256 * 4 + (size_t)N * 4, stream);

  // repack weights to fragment layout (bf16)
  pack_kernel<<<256, 256, 0, stream>>>(W1a, w1aP, 8, 256, 256 * 256);
  pack_kernel<<<256, 256, 0, stream>>>(W1b, w1bP, 8, 256, 256 * 256);
  pack_kernel<<<384, 256, 0, stream>>>(W2a, w2aP, 12, 256, 384 * 256);
  pack_kernel<<<128, 256, 0, stream>>>(W2b, w2bP, 8, 128, 256 * 128);

  count_kernel<<<(E + 255) / 256, 256, 0, stream>>>(ei + E, cnt, E);

  edge_mlp_kernel<<<E / 64, 256, 0, stream>>>(x, ei, ei + E, eattr, b1a, b1b, w1aP, w1bP, agg);

  node_mlp_kernel<<<(N + 63) / 64, 256, 0, stream>>>(x, agg, cnt, b2a, b2b, w2aP, w2bP,
                                                     (float*)d_out, N);
}

// Round 3
// 475.978 us; speedup vs baseline: 1.1008x; 1.1008x over previous
//
#include <hip/hip_runtime.h>
#include <hip/hip_bf16.h>
#include <stdint.h>

typedef short short8 __attribute__((ext_vector_type(8)));
typedef float f32x4 __attribute__((ext_vector_type(4)));
typedef float fvec4 __attribute__((ext_vector_type(4)));
typedef unsigned short us4 __attribute__((ext_vector_type(4)));

static __device__ __forceinline__ unsigned short f2bf(float f) {
  union { float f; uint32_t u; } v; v.f = f;
  uint32_t u = v.u;
  return (unsigned short)((u + 0x7FFFu + ((u >> 16) & 1u)) >> 16);
}

static __device__ __forceinline__ float bf2f(unsigned short u) {
  union { uint32_t u; float f; } v; v.u = (uint32_t)u << 16;
  return v.f;
}

static __device__ __forceinline__ float elu_f(float v) {
  return v > 0.0f ? v : expm1f(v);
}

// packed bf16 atomic add: agg[p] += lo, agg[p+1] += hi (device scope)
static __device__ __forceinline__ void atomic_pk_bf16(unsigned short* p, float lo, float hi) {
  uint32_t data = ((uint32_t)f2bf(hi) << 16) | (uint32_t)f2bf(lo);
  asm volatile("global_atomic_pk_add_bf16 %0, %1, off sc1"
               :: "v"((uint64_t)(uintptr_t)p), "v"(data) : "memory");
}

// Pack W[K][Nc] (f32, row-major) into MFMA B-fragment order (bf16):
// dst[((nt*KT + kt)*64 + lane)*8 + i] = bf16(W[32*kt + 8*(lane>>4) + i][16*nt + (lane&15)])
__global__ void pack_kernel(const float* __restrict__ W, unsigned short* __restrict__ dst,
                            int KT, int Nc, int total) {
  int p = blockIdx.x * blockDim.x + threadIdx.x;
  if (p >= total) return;
  int i = p & 7;
  int l = (p >> 3) & 63;
  int rest = p >> 9;
  int kt = rest % KT;
  int nt = rest / KT;
  int krow = kt * 32 + (l >> 4) * 8 + i;
  int col = nt * 16 + (l & 15);
  dst[p] = f2bf(W[(size_t)krow * Nc + col]);
}

#define LDA 264  // 256 + 8 pad (bf16 elems)

// 64 edges per block, 4 waves; wave w owns output cols [64w, 64w+64).
__global__ __launch_bounds__(256, 3) void edge_mlp_kernel(
    const float* __restrict__ x, const int* __restrict__ row_idx,
    const int* __restrict__ col_idx, const float* __restrict__ eattr,
    const float* __restrict__ b1a,
    const unsigned short* __restrict__ w1aP, const unsigned short* __restrict__ w1bP,
    unsigned short* __restrict__ agg, int* __restrict__ cnt) {
  __shared__ unsigned short As[64 * LDA];
  __shared__ int rowi[64];
  __shared__ int dsti[64];
  const int t = threadIdx.x;
  const int e0 = blockIdx.x * 64;

  if (t < 64) {
    int r = row_idx[e0 + t];
    int d = col_idx[e0 + t];
    rowi[t] = r;
    dsti[t] = d;
    atomicAdd(&cnt[d], 1);
  }

  const int w = t >> 6, l = t & 63;
  const int lr = l & 15, lk = l >> 4;
  const unsigned short* B1 = w1aP + (size_t)(w * 32) * 512 + (size_t)l * 8;
  const unsigned short* B2 = w1bP + (size_t)(w * 32) * 512 + (size_t)l * 8;

  // prefetch GEMM1 kt=0 B-frags (independent of LDS staging)
  short8 bA[4], bB[4];
#pragma unroll
  for (int n = 0; n < 4; ++n) bA[n] = *(const short8*)(B1 + n * 4096);

  __syncthreads();

  // stage A: [64 edges][256 feats] as bf16 (x[row] | edge_attr)
  for (int idx = t; idx < 64 * 64; idx += 256) {
    int e = idx >> 6, c4 = idx & 63;
    fvec4 v;
    if (c4 < 32)
      v = *(const fvec4*)(x + (size_t)rowi[e] * 128 + c4 * 4);
    else
      v = __builtin_nontemporal_load((const fvec4*)(eattr + (size_t)(e0 + e) * 128 + (c4 - 32) * 4));
    us4 o;
    o.x = f2bf(v.x); o.y = f2bf(v.y); o.z = f2bf(v.z); o.w = f2bf(v.w);
    *(us4*)(&As[e * LDA + c4 * 4]) = o;
  }
  __syncthreads();

  f32x4 acc[4][4];
  const f32x4 zero4 = {0.f, 0.f, 0.f, 0.f};
#pragma unroll
  for (int mt = 0; mt < 4; ++mt)
#pragma unroll
    for (int nt = 0; nt < 4; ++nt) acc[mt][nt] = zero4;

  // GEMM1: [64,256] x W1a[256,256], B double-buffered
#pragma unroll
  for (int kt = 0; kt < 8; ++kt) {
    short8* bc = (kt & 1) ? bB : bA;
    short8* bn = (kt & 1) ? bA : bB;
    if (kt < 7) {
#pragma unroll
      for (int n = 0; n < 4; ++n) bn[n] = *(const short8*)(B1 + n * 4096 + (kt + 1) * 512);
    }
    short8 a[4];
#pragma unroll
    for (int mt = 0; mt < 4; ++mt)
      a[mt] = *(const short8*)(&As[(mt * 16 + lr) * LDA + kt * 32 + lk * 8]);
#pragma unroll
    for (int mt = 0; mt < 4; ++mt)
#pragma unroll
      for (int nt = 0; nt < 4; ++nt)
        acc[mt][nt] = __builtin_amdgcn_mfma_f32_16x16x32_bf16(a[mt], bc[nt], acc[mt][nt], 0, 0, 0);
  }

  // prefetch GEMM2 kt=0 B-frags (overlaps epilogue1 + barrier)
#pragma unroll
  for (int n = 0; n < 4; ++n) bA[n] = *(const short8*)(B2 + n * 4096);

  __syncthreads();  // everyone done reading As

  // epilogue1: bias + ELU -> bf16, back into As (reused as H)
#pragma unroll
  for (int nt = 0; nt < 4; ++nt) {
    int col = w * 64 + nt * 16 + lr;
    float bias = b1a[col];
#pragma unroll
    for (int mt = 0; mt < 4; ++mt)
#pragma unroll
      for (int j = 0; j < 4; ++j) {
        float v = elu_f(acc[mt][nt][j] + bias);
        As[(mt * 16 + lk * 4 + j) * LDA + col] = f2bf(v);
      }
  }
  __syncthreads();

  // GEMM2: H[64,256] x W1b[256,256], B double-buffered
#pragma unroll
  for (int mt = 0; mt < 4; ++mt)
#pragma unroll
    for (int nt = 0; nt < 4; ++nt) acc[mt][nt] = zero4;
#pragma unroll
  for (int kt = 0; kt < 8; ++kt) {
    short8* bc = (kt & 1) ? bB : bA;
    short8* bn = (kt & 1) ? bA : bB;
    if (kt < 7) {
#pragma unroll
      for (int n = 0; n < 4; ++n) bn[n] = *(const short8*)(B2 + n * 4096 + (kt + 1) * 512);
    }
    short8 a[4];
#pragma unroll
    for (int mt = 0; mt < 4; ++mt)
      a[mt] = *(const short8*)(&As[(mt * 16 + lr) * LDA + kt * 32 + lk * 8]);
#pragma unroll
    for (int mt = 0; mt < 4; ++mt)
#pragma unroll
      for (int nt = 0; nt < 4; ++nt)
        acc[mt][nt] = __builtin_amdgcn_mfma_f32_16x16x32_bf16(a[mt], bc[nt], acc[mt][nt], 0, 0, 0);
  }

  // epilogue2: pair adjacent cols via shfl_xor(1), packed bf16 atomic scatter.
  // No bias here: b1b is added in node kernel (mean(h+b) == mean(h)+b).
  const int odd = lr & 1;
  const int colbase = w * 64 + (lr & ~1);
#pragma unroll
  for (int nt = 0; nt < 4; ++nt) {
#pragma unroll
    for (int mt = 0; mt < 4; ++mt) {
      float q0 = __shfl_xor(acc[mt][nt][0], 1);
      float q1 = __shfl_xor(acc[mt][nt][1], 1);
      float q2 = __shfl_xor(acc[mt][nt][2], 1);
      float q3 = __shfl_xor(acc[mt][nt][3], 1);
      // even lanes handle rows j=0,1 ; odd lanes rows j=2,3
      int rbase = mt * 16 + lk * 4 + (odd ? 2 : 0);
      float lo1 = odd ? q2 : acc[mt][nt][0];
      float hi1 = odd ? acc[mt][nt][2] : q0;
      float lo2 = odd ? q3 : acc[mt][nt][1];
      float hi2 = odd ? acc[mt][nt][3] : q1;
      int n1 = dsti[rbase];
      int n2 = dsti[rbase + 1];
      int cc = colbase + nt * 16;
      atomic_pk_bf16(agg + ((size_t)n1 << 8) + cc, lo1, hi1);
      atomic_pk_bf16(agg + ((size_t)n2 << 8) + cc, lo2, hi2);
    }
  }
}

#define LDN 392  // 384 + 8 pad

// 64 nodes per block, 4 waves. GEMM1: K=384 -> 256 (ELU), GEMM2: K=256 -> 128.
__global__ __launch_bounds__(256, 3) void node_mlp_kernel(
    const float* __restrict__ x, const unsigned short* __restrict__ agg,
    const int* __restrict__ cnt, const float* __restrict__ b1b,
    const float* __restrict__ b2a, const float* __restrict__ b2b,
    const unsigned short* __restrict__ w2aP, const unsigned short* __restrict__ w2bP,
    float* __restrict__ out, int N) {
  __shared__ unsigned short As[64 * LDN];
  const int t = threadIdx.x;
  const int n0 = blockIdx.x * 64;

  const int w = t >> 6, l = t & 63;
  const int lr = l & 15, lk = l >> 4;
  const unsigned short* B1 = w2aP + (size_t)(w * 48) * 512 + (size_t)l * 8;
  const unsigned short* B2 = w2bP + (size_t)(w * 16) * 512 + (size_t)l * 8;

  short8 bA[4], bB[4];
#pragma unroll
  for (int n = 0; n < 4; ++n) bA[n] = *(const short8*)(B1 + n * 6144);

  // stage A: [64 nodes][384] = bf16( x[n] | agg[n]/max(cnt,1) + b1b )
  for (int idx = t; idx < 64 * 96; idx += 256) {
    int nn = idx / 96;
    int c4 = idx - nn * 96;
    int node = n0 + nn;
    fvec4 v = {0.f, 0.f, 0.f, 0.f};
    if (node < N) {
      if (c4 < 32) {
        v = *(const fvec4*)(x + (size_t)node * 128 + c4 * 4);
      } else {
        int c = (c4 - 32) * 4;
        float cn = (float)cnt[node];
        float inv = cn > 0.f ? 1.0f / cn : 0.f;
        float g = cn > 0.f ? 1.f : 0.f;
        us4 s = *(const us4*)(agg + ((size_t)node << 8) + c);
        v.x = bf2f(s.x) * inv + g * b1b[c + 0];
        v.y = bf2f(s.y) * inv + g * b1b[c + 1];
        v.z = bf2f(s.z) * inv + g * b1b[c + 2];
        v.w = bf2f(s.w) * inv + g * b1b[c + 3];
      }
    }
    us4 o;
    o.x = f2bf(v.x); o.y = f2bf(v.y); o.z = f2bf(v.z); o.w = f2bf(v.w);
    *(us4*)(&As[nn * LDN + c4 * 4]) = o;
  }
  __syncthreads();

  const f32x4 zero4 = {0.f, 0.f, 0.f, 0.f};
  f32x4 acc[4][4];
#pragma unroll
  for (int mt = 0; mt < 4; ++mt)
#pragma unroll
    for (int nt = 0; nt < 4; ++nt) acc[mt][nt] = zero4;

  // GEMM1: [64,384] x W2a[384,256], B double-buffered
#pragma unroll
  for (int kt = 0; kt < 12; ++kt) {
    short8* bc = (kt & 1) ? bB : bA;
    short8* bn = (kt & 1) ? bA : bB;
    if (kt < 11) {
#pragma unroll
      for (int n = 0; n < 4; ++n) bn[n] = *(const short8*)(B1 + n * 6144 + (kt + 1) * 512);
    }
    short8 a[4];
#pragma unroll
    for (int mt = 0; mt < 4; ++mt)
      a[mt] = *(const short8*)(&As[(mt * 16 + lr) * LDN + kt * 32 + lk * 8]);
#pragma unroll
    for (int mt = 0; mt < 4; ++mt)
#pragma unroll
      for (int nt = 0; nt < 4; ++nt)
        acc[mt][nt] = __builtin_amdgcn_mfma_f32_16x16x32_bf16(a[mt], bc[nt], acc[mt][nt], 0, 0, 0);
  }

  // prefetch GEMM2 kt=0
#pragma unroll
  for (int n = 0; n < 2; ++n) bA[n] = *(const short8*)(B2 + n * 4096);

  __syncthreads();  // done reading As

  // epilogue1: bias + ELU -> H (reuse As, stride 264)
#pragma unroll
  for (int nt = 0; nt < 4; ++nt) {
    int col = w * 64 + nt * 16 + lr;
    float bias = b2a[col];
#pragma unroll
    for (int mt = 0; mt < 4; ++mt)
#pragma unroll
      for (int j = 0; j < 4; ++j) {
        float v = elu_f(acc[mt][nt][j] + bias);
        As[(mt * 16 + lk * 4 + j) * 264 + col] = f2bf(v);
      }
  }
  __syncthreads();

  // GEMM2: H[64,256] x W2b[256,128]; wave w owns cols [32w, 32w+32)
  f32x4 acc2[4][2];
#pragma unroll
  for (int mt = 0; mt < 4; ++mt)
#pragma unroll
    for (int nt = 0; nt < 2; ++nt) acc2[mt][nt] = zero4;
#pragma unroll
  for (int kt = 0; kt < 8; ++kt) {
    short8* bc = (kt & 1) ? bB : bA;
    short8* bn = (kt & 1) ? bA : bB;
    if (kt < 7) {
#pragma unroll
      for (int n = 0; n < 2; ++n) bn[n] = *(const short8*)(B2 + n * 4096 + (kt + 1) * 512);
    }
    short8 a[4];
#pragma unroll
    for (int mt = 0; mt < 4; ++mt)
      a[mt] = *(const short8*)(&As[(mt * 16 + lr) * 264 + kt * 32 + lk * 8]);
#pragma unroll
    for (int mt = 0; mt < 4; ++mt)
#pragma unroll
      for (int nt = 0; nt < 2; ++nt)
        acc2[mt][nt] = __builtin_amdgcn_mfma_f32_16x16x32_bf16(a[mt], bc[nt], acc2[mt][nt], 0, 0, 0);
  }

  // epilogue2: bias + store
#pragma unroll
  for (int nt = 0; nt < 2; ++nt) {
    int col = w * 32 + nt * 16 + lr;
    float bias = b2b[col];
#pragma unroll
    for (int mt = 0; mt < 4; ++mt)
#pragma unroll
      for (int j = 0; j < 4; ++j) {
        int node = n0 + mt * 16 + lk * 4 + j;
        if (node < N) out[(size_t)node * 128 + col] = acc2[mt][nt][j] + bias;
      }
  }
}

extern "C" void kernel_launch(void* const* d_in, const int* in_sizes, int n_in,
                              void* d_out, int out_size, void* d_ws, size_t ws_size,
                              hipStream_t stream) {
  const float* x = (const float*)d_in[0];
  const int* ei = (const int*)d_in[1];
  const float* eattr = (const float*)d_in[2];
  // d_in[3] = u, d_in[4] = batch : unused by the reference
  const float* W1a = (const float*)d_in[5];
  const float* b1a = (const float*)d_in[6];
  const float* W1b = (const float*)d_in[7];
  const float* b1b = (const float*)d_in[8];
  const float* W2a = (const float*)d_in[9];
  const float* b2a = (const float*)d_in[10];
  const float* W2b = (const float*)d_in[11];
  const float* b2b = (const float*)d_in[12];

  const int N = in_sizes[0] / 128;   // 25000
  const int E = in_sizes[2] / 128;   // 400000

  char* ws = (char*)d_ws;
  unsigned short* agg = (unsigned short*)ws;                 // N*256 bf16
  int* cnt = (int*)(ws + (size_t)N * 256 * 2);               // N int
  size_t off = (size_t)N * 256 * 2 + (size_t)N * 4;
  off = (off + 255) & ~(size_t)255;
  unsigned short* w1aP = (unsigned short*)(ws + off); off += 256 * 256 * 2;
  unsigned short* w1bP = (unsigned short*)(ws + off); off += 256 * 256 * 2;
  unsigned short* w2aP = (unsigned short*)(ws + off); off += 384 * 256 * 2;
  unsigned short* w2bP = (unsigned short*)(ws + off); off += 256 * 128 * 2;

  // zero agg sums + counts (accumulated via atomics each launch)
  (void)hipMemsetAsync(ws, 0, (size_t)N * 256 * 2 + (size_t)N * 4, stream);

  // repack weights to fragment layout (bf16)
  pack_kernel<<<256, 256, 0, stream>>>(W1a, w1aP, 8, 256, 256 * 256);
  pack_kernel<<<256, 256, 0, stream>>>(W1b, w1bP, 8, 256, 256 * 256);
  pack_kernel<<<384, 256, 0, stream>>>(W2a, w2aP, 12, 256, 384 * 256);
  pack_kernel<<<128, 256, 0, stream>>>(W2b, w2bP, 8, 128, 256 * 128);

  edge_mlp_kernel<<<E / 64, 256, 0, stream>>>(x, ei, ei + E, eattr, b1a, w1aP, w1bP, agg, cnt);

  node_mlp_kernel<<<(N + 63) / 64, 256, 0, stream>>>(x, agg, cnt, b1b, b2a, b2b, w2aP, w2bP,
                                                     (float*)d_out, N);
}